// Round 6
// baseline (105.684 us; speedup 1.0000x reference)
//
#include <hip/hip_runtime.h>
#include <hip/hip_bf16.h>
#include <stdint.h>

#define NNODES 100000
#define DIN    256
#define DOUT   128
#define KNB    16

typedef __attribute__((ext_vector_type(8))) __bf16 bf16x8;
typedef __attribute__((ext_vector_type(4))) float  f32x4;
typedef __attribute__((ext_vector_type(8))) unsigned short u16x8;

// ---------------------------------------------------------------------------
// Kernel 0: Wt[c][k] = bf16(W[k][c])  (128 x 256 bf16 = 64 KB, L2-resident)
// ---------------------------------------------------------------------------
__global__ __launch_bounds__(256)
void gc_wt(const float* __restrict__ W, unsigned short* __restrict__ Wt)
{
    const int idx = blockIdx.x * 256 + threadIdx.x;   // 0 .. 32767
    const int c = idx >> 8;        // 0..127
    const int k = idx & 255;       // 0..255
    Wt[c * DIN + k] = __builtin_bit_cast(unsigned short, (__bf16)W[k * DOUT + c]);
}

// ---------------------------------------------------------------------------
// Kernel 1: h = relu(feats @ W + b) -> bf16.  (structure unchanged)
// ---------------------------------------------------------------------------
__global__ __launch_bounds__(256, 3)
void gc_linear_relu(const float* __restrict__ feats,
                    const unsigned short* __restrict__ Wt,
                    const float* __restrict__ bias,
                    unsigned short* __restrict__ h)
{
    __shared__ unsigned short As[64 * 256];   // 32 KB bf16, swizzled chunks

    const int t    = threadIdx.x;
    const int lane = t & 63;
    const int wave = t >> 6;                  // 0..3
    const int brow = blockIdx.x * 64;
    const int wcol = wave * 32;
    const int fr   = lane & 15;
    const int kb   = lane >> 4;               // 0..3

    // ---- stage A: issue all 16 global loads first ----
    f32x4 sa[8], sb[8];
    int   srow[8], schk[8];
    #pragma unroll
    for (int i = 0; i < 8; ++i) {
        const int id = i * 256 + t;           // 16B-chunk id, 0..2047
        const int r  = id >> 5;               // 0..63
        const int c  = id & 31;               // chunk within row
        int gr = brow + r; if (gr >= NNODES) gr = NNODES - 1;
        const float* ap = feats + (size_t)gr * DIN + c * 8;
        sa[i] = __builtin_nontemporal_load(reinterpret_cast<const f32x4*>(ap));
        sb[i] = __builtin_nontemporal_load(reinterpret_cast<const f32x4*>(ap + 4));
        srow[i] = r;
        schk[i] = c ^ (r & 15);               // XOR swizzle
    }

    // ---- B fragments from Wt: 16 x 16B L2 loads, independent of staging ----
    bf16x8 bfrag[2][8];
    #pragma unroll
    for (int ct = 0; ct < 2; ++ct) {
        const unsigned short* wp = Wt + (wcol + ct * 16 + fr) * DIN;
        #pragma unroll
        for (int ks = 0; ks < 8; ++ks)
            bfrag[ct][ks] = __builtin_bit_cast(bf16x8,
                *reinterpret_cast<const u16x8*>(wp + ks * 32 + kb * 8));
    }

    #pragma unroll
    for (int i = 0; i < 8; ++i) {
        bf16x8 v;
        v[0] = (__bf16)sa[i][0]; v[1] = (__bf16)sa[i][1];
        v[2] = (__bf16)sa[i][2]; v[3] = (__bf16)sa[i][3];
        v[4] = (__bf16)sb[i][0]; v[5] = (__bf16)sb[i][1];
        v[6] = (__bf16)sb[i][2]; v[7] = (__bf16)sb[i][3];
        *reinterpret_cast<bf16x8*>(&As[srow[i] * 256 + schk[i] * 8]) = v;
    }
    __syncthreads();

    // ---- MFMA ----
    f32x4 acc[4][2];
    #pragma unroll
    for (int rt = 0; rt < 4; ++rt)
        #pragma unroll
        for (int ct = 0; ct < 2; ++ct)
            acc[rt][ct] = (f32x4){0.f, 0.f, 0.f, 0.f};

    #pragma unroll
    for (int rt = 0; rt < 4; ++rt) {
        const int row = rt * 16 + fr;
        #pragma unroll
        for (int ks = 0; ks < 8; ++ks) {
            const int chunk = (ks * 4 + kb) ^ fr;   // row&15 == fr
            const bf16x8 af = *reinterpret_cast<const bf16x8*>(&As[row * 256 + chunk * 8]);
            acc[rt][0] = __builtin_amdgcn_mfma_f32_16x16x32_bf16(bfrag[0][ks], af, acc[rt][0], 0, 0, 0);
            acc[rt][1] = __builtin_amdgcn_mfma_f32_16x16x32_bf16(bfrag[1][ks], af, acc[rt][1], 0, 0, 0);
        }
    }

    // ---- epilogue: h[brow+rt*16+fr][wcol+ct*16+kb*4 + r], r=0..3 ----
    #pragma unroll
    for (int rt = 0; rt < 4; ++rt) {
        const int grow = brow + rt * 16 + fr;
        if (grow < NNODES) {
            #pragma unroll
            for (int ct = 0; ct < 2; ++ct) {
                const int colb = wcol + ct * 16 + kb * 4;
                union { unsigned short us[4]; uint2 v; } o;
                o.us[0] = __builtin_bit_cast(unsigned short, (__bf16)fmaxf(acc[rt][ct][0] + bias[colb + 0], 0.f));
                o.us[1] = __builtin_bit_cast(unsigned short, (__bf16)fmaxf(acc[rt][ct][1] + bias[colb + 1], 0.f));
                o.us[2] = __builtin_bit_cast(unsigned short, (__bf16)fmaxf(acc[rt][ct][2] + bias[colb + 2], 0.f));
                o.us[3] = __builtin_bit_cast(unsigned short, (__bf16)fmaxf(acc[rt][ct][3] + bias[colb + 3], 0.f));
                *reinterpret_cast<uint2*>(h + (size_t)grow * DOUT + colb) = o.v;
            }
        }
    }
}

// ---------------------------------------------------------------------------
// Kernel 2: out[i][:] = mean_k h[edge[i][k]][:]
// 16 nodes / 256-thr block; 16 lanes/node, 16B/lane.
// Two pinned phases: (A) issue ALL 16 gather loads, (B) reduce.
// sched_barrier(0) stops the compiler from sinking loads into the reduce
// (R5 showed it re-rolls the loop: VGPR stayed 40, zero MLP gain).
// ---------------------------------------------------------------------------
__global__ __launch_bounds__(256, 4)
void gc_gather_mean(const int* __restrict__ edge,
                    const unsigned short* __restrict__ h,
                    float* __restrict__ out)
{
    const int t    = threadIdx.x;
    const int grp  = t >> 4;          // node within block (0..15)
    const int c4   = t & 15;          // 16B chunk within row == k index
    const int node = blockIdx.x * 16 + grp;
    const int gbase = (t & 63) & 48;  // 16-lane group base within wave

    const int nb_mine = edge[node * KNB + c4];   // lane c4 holds neighbor k=c4

    // ---- phase A: issue ALL 16 gather loads (kept live past the barrier) --
    u16x8 v0  = *reinterpret_cast<const u16x8*>(h + (size_t)__shfl(nb_mine, gbase | 0)  * DOUT + c4 * 8);
    u16x8 v1  = *reinterpret_cast<const u16x8*>(h + (size_t)__shfl(nb_mine, gbase | 1)  * DOUT + c4 * 8);
    u16x8 v2  = *reinterpret_cast<const u16x8*>(h + (size_t)__shfl(nb_mine, gbase | 2)  * DOUT + c4 * 8);
    u16x8 v3  = *reinterpret_cast<const u16x8*>(h + (size_t)__shfl(nb_mine, gbase | 3)  * DOUT + c4 * 8);
    u16x8 v4  = *reinterpret_cast<const u16x8*>(h + (size_t)__shfl(nb_mine, gbase | 4)  * DOUT + c4 * 8);
    u16x8 v5  = *reinterpret_cast<const u16x8*>(h + (size_t)__shfl(nb_mine, gbase | 5)  * DOUT + c4 * 8);
    u16x8 v6  = *reinterpret_cast<const u16x8*>(h + (size_t)__shfl(nb_mine, gbase | 6)  * DOUT + c4 * 8);
    u16x8 v7  = *reinterpret_cast<const u16x8*>(h + (size_t)__shfl(nb_mine, gbase | 7)  * DOUT + c4 * 8);
    u16x8 v8  = *reinterpret_cast<const u16x8*>(h + (size_t)__shfl(nb_mine, gbase | 8)  * DOUT + c4 * 8);
    u16x8 v9  = *reinterpret_cast<const u16x8*>(h + (size_t)__shfl(nb_mine, gbase | 9)  * DOUT + c4 * 8);
    u16x8 v10 = *reinterpret_cast<const u16x8*>(h + (size_t)__shfl(nb_mine, gbase | 10) * DOUT + c4 * 8);
    u16x8 v11 = *reinterpret_cast<const u16x8*>(h + (size_t)__shfl(nb_mine, gbase | 11) * DOUT + c4 * 8);
    u16x8 v12 = *reinterpret_cast<const u16x8*>(h + (size_t)__shfl(nb_mine, gbase | 12) * DOUT + c4 * 8);
    u16x8 v13 = *reinterpret_cast<const u16x8*>(h + (size_t)__shfl(nb_mine, gbase | 13) * DOUT + c4 * 8);
    u16x8 v14 = *reinterpret_cast<const u16x8*>(h + (size_t)__shfl(nb_mine, gbase | 14) * DOUT + c4 * 8);
    u16x8 v15 = *reinterpret_cast<const u16x8*>(h + (size_t)__shfl(nb_mine, gbase | 15) * DOUT + c4 * 8);

    __builtin_amdgcn_sched_barrier(0);   // pin: no load sinks past this point

    // ---- phase B: reduce ----
    float s[8];
    #pragma unroll
    for (int j = 0; j < 8; ++j) s[j] = 0.f;

    const u16x8* vs[16] = {&v0,&v1,&v2,&v3,&v4,&v5,&v6,&v7,
                           &v8,&v9,&v10,&v11,&v12,&v13,&v14,&v15};
    #pragma unroll
    for (int k = 0; k < KNB; ++k) {
        const uint32_t* pw = reinterpret_cast<const uint32_t*>(vs[k]);
        #pragma unroll
        for (int p = 0; p < 4; ++p) {
            union { uint32_t u; float f; } lo, hi;
            lo.u = pw[p] << 16;
            hi.u = pw[p] & 0xFFFF0000u;
            s[2 * p]     += lo.f;
            s[2 * p + 1] += hi.f;
        }
    }

    float* op = out + (size_t)node * DOUT + c4 * 8;
    f32x4 o0 = {s[0] * 0.0625f, s[1] * 0.0625f, s[2] * 0.0625f, s[3] * 0.0625f};
    f32x4 o1 = {s[4] * 0.0625f, s[5] * 0.0625f, s[6] * 0.0625f, s[7] * 0.0625f};
    __builtin_nontemporal_store(o0, reinterpret_cast<f32x4*>(op));
    __builtin_nontemporal_store(o1, reinterpret_cast<f32x4*>(op + 4));
}

extern "C" void kernel_launch(void* const* d_in, const int* in_sizes, int n_in,
                              void* d_out, int out_size, void* d_ws, size_t ws_size,
                              hipStream_t stream)
{
    const float* feats = (const float*)d_in[0];
    const int*   edge  = (const int*)d_in[1];
    const float* W     = (const float*)d_in[2];
    const float* bias  = (const float*)d_in[3];
    float* out = (float*)d_out;

    const size_t h_bytes  = (size_t)NNODES * DOUT * sizeof(unsigned short); // 25.6 MB
    const size_t wt_bytes = (size_t)DIN * DOUT * sizeof(unsigned short);    // 64 KB

    unsigned short* h = (unsigned short*)d_ws;
    unsigned short* Wt;
    if (ws_size >= h_bytes + wt_bytes)
        Wt = (unsigned short*)((char*)d_ws + h_bytes);
    else
        Wt = (unsigned short*)d_out;   // gather fully overwrites d_out later

    gc_wt<<<(DIN * DOUT) / 256, 256, 0, stream>>>(W, Wt);

    const int gemm_blocks = (NNODES + 63) / 64;     // 1563
    gc_linear_relu<<<gemm_blocks, 256, 0, stream>>>(feats, Wt, bias, h);

    const int gat_blocks = NNODES / 16;             // 6250, exact
    gc_gather_mean<<<gat_blocks, 256, 0, stream>>>(edge, h, out);
}

// Round 8
// 105.610 us; speedup vs baseline: 1.0007x; 1.0007x over previous
//
#include <hip/hip_runtime.h>
#include <hip/hip_bf16.h>
#include <stdint.h>

#define NNODES 100000
#define DIN    256
#define DOUT   128
#define KNB    16

typedef __attribute__((ext_vector_type(8))) __bf16 bf16x8;
typedef __attribute__((ext_vector_type(4))) float  f32x4;
typedef __attribute__((ext_vector_type(8))) unsigned short u16x8;
typedef __attribute__((ext_vector_type(4))) uint32_t u32x4;

// ---------------------------------------------------------------------------
// Kernel 0: Wt[c][k] = bf16(W[k][c])  (128 x 256 bf16 = 64 KB, L2-resident)
// ---------------------------------------------------------------------------
__global__ __launch_bounds__(256)
void gc_wt(const float* __restrict__ W, unsigned short* __restrict__ Wt)
{
    const int idx = blockIdx.x * 256 + threadIdx.x;   // 0 .. 32767
    const int c = idx >> 8;        // 0..127
    const int k = idx & 255;       // 0..255
    Wt[c * DIN + k] = __builtin_bit_cast(unsigned short, (__bf16)W[k * DOUT + c]);
}

// ---------------------------------------------------------------------------
// Kernel 1: h = relu(feats @ W + b) -> bf16.  (structure unchanged from R4)
// ---------------------------------------------------------------------------
__global__ __launch_bounds__(256, 3)
void gc_linear_relu(const float* __restrict__ feats,
                    const unsigned short* __restrict__ Wt,
                    const float* __restrict__ bias,
                    unsigned short* __restrict__ h)
{
    __shared__ unsigned short As[64 * 256];   // 32 KB bf16, swizzled chunks

    const int t    = threadIdx.x;
    const int lane = t & 63;
    const int wave = t >> 6;                  // 0..3
    const int brow = blockIdx.x * 64;
    const int wcol = wave * 32;
    const int fr   = lane & 15;
    const int kb   = lane >> 4;               // 0..3

    // ---- stage A: issue all 16 global loads first ----
    f32x4 sa[8], sb[8];
    int   srow[8], schk[8];
    #pragma unroll
    for (int i = 0; i < 8; ++i) {
        const int id = i * 256 + t;           // 16B-chunk id, 0..2047
        const int r  = id >> 5;               // 0..63
        const int c  = id & 31;               // chunk within row
        int gr = brow + r; if (gr >= NNODES) gr = NNODES - 1;
        const float* ap = feats + (size_t)gr * DIN + c * 8;
        sa[i] = __builtin_nontemporal_load(reinterpret_cast<const f32x4*>(ap));
        sb[i] = __builtin_nontemporal_load(reinterpret_cast<const f32x4*>(ap + 4));
        srow[i] = r;
        schk[i] = c ^ (r & 15);               // XOR swizzle
    }

    // ---- B fragments from Wt: 16 x 16B L2 loads, independent of staging ----
    bf16x8 bfrag[2][8];
    #pragma unroll
    for (int ct = 0; ct < 2; ++ct) {
        const unsigned short* wp = Wt + (wcol + ct * 16 + fr) * DIN;
        #pragma unroll
        for (int ks = 0; ks < 8; ++ks)
            bfrag[ct][ks] = __builtin_bit_cast(bf16x8,
                *reinterpret_cast<const u16x8*>(wp + ks * 32 + kb * 8));
    }

    #pragma unroll
    for (int i = 0; i < 8; ++i) {
        bf16x8 v;
        v[0] = (__bf16)sa[i][0]; v[1] = (__bf16)sa[i][1];
        v[2] = (__bf16)sa[i][2]; v[3] = (__bf16)sa[i][3];
        v[4] = (__bf16)sb[i][0]; v[5] = (__bf16)sb[i][1];
        v[6] = (__bf16)sb[i][2]; v[7] = (__bf16)sb[i][3];
        *reinterpret_cast<bf16x8*>(&As[srow[i] * 256 + schk[i] * 8]) = v;
    }
    __syncthreads();

    // ---- MFMA ----
    f32x4 acc[4][2];
    #pragma unroll
    for (int rt = 0; rt < 4; ++rt)
        #pragma unroll
        for (int ct = 0; ct < 2; ++ct)
            acc[rt][ct] = (f32x4){0.f, 0.f, 0.f, 0.f};

    #pragma unroll
    for (int rt = 0; rt < 4; ++rt) {
        const int row = rt * 16 + fr;
        #pragma unroll
        for (int ks = 0; ks < 8; ++ks) {
            const int chunk = (ks * 4 + kb) ^ fr;   // row&15 == fr
            const bf16x8 af = *reinterpret_cast<const bf16x8*>(&As[row * 256 + chunk * 8]);
            acc[rt][0] = __builtin_amdgcn_mfma_f32_16x16x32_bf16(bfrag[0][ks], af, acc[rt][0], 0, 0, 0);
            acc[rt][1] = __builtin_amdgcn_mfma_f32_16x16x32_bf16(bfrag[1][ks], af, acc[rt][1], 0, 0, 0);
        }
    }

    // ---- epilogue ----
    #pragma unroll
    for (int rt = 0; rt < 4; ++rt) {
        const int grow = brow + rt * 16 + fr;
        if (grow < NNODES) {
            #pragma unroll
            for (int ct = 0; ct < 2; ++ct) {
                const int colb = wcol + ct * 16 + kb * 4;
                union { unsigned short us[4]; uint2 v; } o;
                o.us[0] = __builtin_bit_cast(unsigned short, (__bf16)fmaxf(acc[rt][ct][0] + bias[colb + 0], 0.f));
                o.us[1] = __builtin_bit_cast(unsigned short, (__bf16)fmaxf(acc[rt][ct][1] + bias[colb + 1], 0.f));
                o.us[2] = __builtin_bit_cast(unsigned short, (__bf16)fmaxf(acc[rt][ct][2] + bias[colb + 2], 0.f));
                o.us[3] = __builtin_bit_cast(unsigned short, (__bf16)fmaxf(acc[rt][ct][3] + bias[colb + 3], 0.f));
                *reinterpret_cast<uint2*>(h + (size_t)grow * DOUT + colb) = o.v;
            }
        }
    }
}

// ---------------------------------------------------------------------------
// Kernel 2: out[i][:] = mean_k h[edge[i][k]][:]
// 16 nodes / 256-thr block; 16 lanes/node, 16B/lane.
// Forced MLP: 16 asm-volatile global_load_dwordx4 issued back-to-back, then
// ONE s_waitcnt vmcnt(0) that TIES all 16 result vectors ("+v") so every
// consumer is data-dependent on the waitcnt (fixes R7's rule-#18 hoist-NaN),
// plus sched_barrier(0).
// ---------------------------------------------------------------------------
__global__ __launch_bounds__(256, 4)
void gc_gather_mean(const int* __restrict__ edge,
                    const unsigned short* __restrict__ h,
                    float* __restrict__ out)
{
    const int t    = threadIdx.x;
    const int grp  = t >> 4;          // node within block (0..15)
    const int c4   = t & 15;          // 16B chunk within row == k index
    const int node = blockIdx.x * 16 + grp;
    const int gbase = (t & 63) & 48;  // 16-lane group base within wave

    const int nb_mine = edge[node * KNB + c4];   // lane c4 holds neighbor k=c4

    u32x4 v0, v1, v2, v3, v4, v5, v6, v7, v8, v9, v10, v11, v12, v13, v14, v15;

#define GLOAD(vk, kidx)                                                        \
    {                                                                          \
        const unsigned short* p =                                              \
            h + (size_t)__shfl(nb_mine, gbase | (kidx)) * DOUT + c4 * 8;       \
        asm volatile("global_load_dwordx4 %0, %1, off"                         \
                     : "=v"(vk) : "v"(p));                                     \
    }
    GLOAD(v0, 0)   GLOAD(v1, 1)   GLOAD(v2, 2)   GLOAD(v3, 3)
    GLOAD(v4, 4)   GLOAD(v5, 5)   GLOAD(v6, 6)   GLOAD(v7, 7)
    GLOAD(v8, 8)   GLOAD(v9, 9)   GLOAD(v10, 10) GLOAD(v11, 11)
    GLOAD(v12, 12) GLOAD(v13, 13) GLOAD(v14, 14) GLOAD(v15, 15)
#undef GLOAD

    // Tie every result register THROUGH the waitcnt: consumers now depend on
    // this asm, not just the loads, so nothing can hoist above it (rule #18).
    asm volatile("s_waitcnt vmcnt(0)"
                 : "+v"(v0), "+v"(v1), "+v"(v2),  "+v"(v3),
                   "+v"(v4), "+v"(v5), "+v"(v6),  "+v"(v7),
                   "+v"(v8), "+v"(v9), "+v"(v10), "+v"(v11),
                   "+v"(v12), "+v"(v13), "+v"(v14), "+v"(v15)
                 :
                 : "memory");
    __builtin_amdgcn_sched_barrier(0);

    float s0 = 0.f, s1 = 0.f, s2 = 0.f, s3 = 0.f;
    float s4 = 0.f, s5 = 0.f, s6 = 0.f, s7 = 0.f;

#define ACC(vk)                                                                \
    {                                                                          \
        union { uint32_t u; float f; } lo, hi;                                 \
        lo.u = vk[0] << 16;          s0 += lo.f;                               \
        hi.u = vk[0] & 0xFFFF0000u;  s1 += hi.f;                               \
        lo.u = vk[1] << 16;          s2 += lo.f;                               \
        hi.u = vk[1] & 0xFFFF0000u;  s3 += hi.f;                               \
        lo.u = vk[2] << 16;          s4 += lo.f;                               \
        hi.u = vk[2] & 0xFFFF0000u;  s5 += hi.f;                               \
        lo.u = vk[3] << 16;          s6 += lo.f;                               \
        hi.u = vk[3] & 0xFFFF0000u;  s7 += hi.f;                               \
    }
    ACC(v0)  ACC(v1)  ACC(v2)  ACC(v3)
    ACC(v4)  ACC(v5)  ACC(v6)  ACC(v7)
    ACC(v8)  ACC(v9)  ACC(v10) ACC(v11)
    ACC(v12) ACC(v13) ACC(v14) ACC(v15)
#undef ACC

    float* op = out + (size_t)node * DOUT + c4 * 8;
    f32x4 o0 = {s0 * 0.0625f, s1 * 0.0625f, s2 * 0.0625f, s3 * 0.0625f};
    f32x4 o1 = {s4 * 0.0625f, s5 * 0.0625f, s6 * 0.0625f, s7 * 0.0625f};
    __builtin_nontemporal_store(o0, reinterpret_cast<f32x4*>(op));
    __builtin_nontemporal_store(o1, reinterpret_cast<f32x4*>(op + 4));
}

extern "C" void kernel_launch(void* const* d_in, const int* in_sizes, int n_in,
                              void* d_out, int out_size, void* d_ws, size_t ws_size,
                              hipStream_t stream)
{
    const float* feats = (const float*)d_in[0];
    const int*   edge  = (const int*)d_in[1];
    const float* W     = (const float*)d_in[2];
    const float* bias  = (const float*)d_in[3];
    float* out = (float*)d_out;

    const size_t h_bytes  = (size_t)NNODES * DOUT * sizeof(unsigned short); // 25.6 MB
    const size_t wt_bytes = (size_t)DIN * DOUT * sizeof(unsigned short);    // 64 KB

    unsigned short* h = (unsigned short*)d_ws;
    unsigned short* Wt;
    if (ws_size >= h_bytes + wt_bytes)
        Wt = (unsigned short*)((char*)d_ws + h_bytes);
    else
        Wt = (unsigned short*)d_out;   // gather fully overwrites d_out later

    gc_wt<<<(DIN * DOUT) / 256, 256, 0, stream>>>(W, Wt);

    const int gemm_blocks = (NNODES + 63) / 64;     // 1563
    gc_linear_relu<<<gemm_blocks, 256, 0, stream>>>(feats, Wt, bias, h);

    const int gat_blocks = NNODES / 16;             // 6250, exact
    gc_gather_mean<<<gat_blocks, 256, 0, stream>>>(edge, h, out);
}